// Round 5
// baseline (549.583 us; speedup 1.0000x reference)
//
#include <hip/hip_runtime.h>

#define NUM_CLASSES 601
#define OUT_DIM 27
#define P_ELEMS (NUM_CLASSES * OUT_DIM)   // 16227 floats = 64908 B (workspace)

typedef float vfloat4 __attribute__((ext_vector_type(4)));

// Kernel A: softmax each row of W into workspace P. Arithmetic (sequential
// __expf sum, multiply by reciprocal) is identical to the previous in-LDS
// preamble -> bit-identical output. Runs once on 3 blocks; ~2 us.
__global__ __launch_bounds__(256)
void softmax_rows_kernel(const float* __restrict__ W, float* __restrict__ P) {
    const unsigned row = blockIdx.x * 256u + threadIdx.x;
    if (row >= NUM_CLASSES) return;
    const float* w = W + row * OUT_DIM;
    float* p = P + row * OUT_DIM;
    float s = 0.f;
    #pragma unroll
    for (int j = 0; j < OUT_DIM; ++j) { const float v = __expf(w[j]); p[j] = v; s += v; }
    const float inv = 1.0f / s;
    #pragma unroll
    for (int j = 0; j < OUT_DIM; ++j) p[j] *= inv;
}

// Kernel B: pure gather-store stream. No LDS, no barriers, 256-thread blocks
// (the config the 6.3 TB/s harness fill kernel runs), ~20 VGPRs -> occupancy
// is not resource-limited. P (64 KB) is L1/L2-resident; idx (16 MB) L2-resident
// with high spatial locality (consecutive lanes share rows).
__global__ __launch_bounds__(256)
void gather_store_kernel(const int* __restrict__ idx,
                         const float* __restrict__ P,
                         float4* __restrict__ out4,
                         unsigned n4) {
    unsigned i = blockIdx.x * 256u + threadIdx.x;
    const unsigned stride = gridDim.x * 256u;   // 1048576 threads -> 27 iters
    for (; i < n4; i += stride) {
        const unsigned e  = i * 4u;
        const unsigned r0 = e / 27u;              // magic-multiply
        const unsigned c0 = e - r0 * 27u;
        const unsigned r1 = r0 + (c0 >= 24u);     // float4 spans row r0+1 iff c0 >= 24
        const unsigned b0 = (unsigned)idx[r0] * 27u;
        const unsigned b1 = (unsigned)idx[r1] * 27u;
        vfloat4 v;
        #pragma unroll
        for (int k = 0; k < 4; ++k) {
            const unsigned c = c0 + (unsigned)k;
            v[k] = P[(c < 27u) ? (b0 + c) : (b1 + c - 27u)];
        }
        *(vfloat4*)(out4 + i) = v;
    }
}

extern "C" void kernel_launch(void* const* d_in, const int* in_sizes, int n_in,
                              void* d_out, int out_size, void* d_ws, size_t ws_size,
                              hipStream_t stream) {
    const int*   idx = (const int*)d_in[0];   // bigram_idx [4194304] int32
    const float* W   = (const float*)d_in[1]; // W [601,27] float32
    float4*      out = (float4*)d_out;        // probs [4194304,27] float32
    float*       P   = (float*)d_ws;          // 64908 B softmax table in workspace

    // Kernel boundary gives release/acquire ordering; same stream -> A before B.
    softmax_rows_kernel<<<dim3(3), dim3(256), 0, stream>>>(W, P);

    const unsigned n4 = (unsigned)(out_size / 4);  // 28311552 float4 stores
    gather_store_kernel<<<dim3(4096), dim3(256), 0, stream>>>(idx, P, out, n4);
}

// Round 8
// 453.145 us; speedup vs baseline: 1.2128x; 1.2128x over previous
//
#include <hip/hip_runtime.h>

#define NUM_CLASSES 601
#define OUT_DIM 27
#define P_ELEMS (NUM_CLASSES * OUT_DIM)       // 16227 floats = 64908 B
#define ROWS_PER_BLOCK 8192                    // 4194304 / 512 blocks
#define ROWS_PER_CHUNK 4096                    // idx chunk staged in LDS (16 KB)
#define F4_PER_CHUNK  (ROWS_PER_CHUNK * OUT_DIM / 4)   // 27648, = 27 per thread
#define F4_PER_BLOCK  (ROWS_PER_BLOCK * OUT_DIM / 4)   // 55296 (exact, no tail)

typedef float vfloat4 __attribute__((ext_vector_type(4)));
typedef int   vint4   __attribute__((ext_vector_type(4)));

// Monolithic kernel, blocked mapping: block b owns rows [8192b, 8192b+8192)
// -> a contiguous 864 KB store region. Both P and the idx chunk live in LDS
// (81292 B total -> 2 blocks/CU -> 32 waves/CU), so the 27-iter inner loop has
// ZERO vmem loads: only ds_read (lgkmcnt) + global_store. No s_waitcnt vmcnt
// is ever needed in the loop -> stores are fire-and-forget and the per-wave
// iteration no longer waits for the previous store to retire (the round-3
// kernel's suspected serializer).
// Chunk self-containment: 27*4096 % 4 == 0, and the last float4 of a chunk has
// c0 = 23, so r + (c0>=24) never indexes past ROWS_PER_CHUNK-1. No OOB.
__global__ __launch_bounds__(1024, 8)
void trigram_probs_kernel(const int* __restrict__ idx,
                          const float* __restrict__ W,
                          float4* __restrict__ out4) {
    __shared__ float P[P_ELEMS];
    __shared__ __align__(16) int IDX[ROWS_PER_CHUNK];

    const unsigned t = threadIdx.x;
    const unsigned b = blockIdx.x;
    const unsigned row_base = b * ROWS_PER_BLOCK;

    // Issue chunk-0 idx loads first (int4/thread, fully coalesced); they fly
    // while the softmax preamble computes.
    const vint4 c0_idx = *(const vint4*)(idx + row_base + 4u * t);

    // ---- softmax(W) -> P. Same arithmetic order as all previous rounds.
    if (t < NUM_CLASSES) {
        const float* w = W + t * OUT_DIM;
        float* p = P + t * OUT_DIM;
        float s = 0.f;
        #pragma unroll
        for (int j = 0; j < OUT_DIM; ++j) { const float v = __expf(w[j]); p[j] = v; s += v; }
        const float inv = 1.0f / s;
        #pragma unroll
        for (int j = 0; j < OUT_DIM; ++j) p[j] *= inv;
    }

    *(vint4*)(IDX + 4u * t) = c0_idx;
    __syncthreads();

    // Prefetch chunk-1 idx into registers now; consumed after chunk 0. The
    // loads sit in flight / in regs under the whole chunk-0 compute phase.
    const vint4 c1_idx = *(const vint4*)(idx + row_base + ROWS_PER_CHUNK + 4u * t);

    float4* outb = out4 + (size_t)b * F4_PER_BLOCK;

    // ---- chunk 0: thread t handles local float4s {t + 1024j}, j=0..26.
    {
        unsigned eloc = 4u * t;                    // float index within chunk
        for (int j = 0; j < 27; ++j, eloc += 4096u) {
            const unsigned r  = eloc / 27u;        // magic-multiply
            const unsigned cc = eloc - r * 27u;
            const unsigned b0 = (unsigned)IDX[r] * 27u;
            const unsigned b1 = (unsigned)IDX[r + (cc >= 24u)] * 27u;
            vfloat4 v;
            #pragma unroll
            for (int k = 0; k < 4; ++k) {
                const unsigned c = cc + (unsigned)k;
                v[k] = P[(c < 27u) ? (b0 + c) : (b1 + c - 27u)];
            }
            *(vfloat4*)(outb + t + 1024u * j) = v;
        }
    }

    __syncthreads();                               // all reads of IDX chunk 0 done
    *(vint4*)(IDX + 4u * t) = c1_idx;
    __syncthreads();

    // ---- chunk 1: identical, shifted by 4096 rows / 27648 float4s.
    {
        float4* outc = outb + F4_PER_CHUNK;
        unsigned eloc = 4u * t;
        for (int j = 0; j < 27; ++j, eloc += 4096u) {
            const unsigned r  = eloc / 27u;
            const unsigned cc = eloc - r * 27u;
            const unsigned b0 = (unsigned)IDX[r] * 27u;
            const unsigned b1 = (unsigned)IDX[r + (cc >= 24u)] * 27u;
            vfloat4 v;
            #pragma unroll
            for (int k = 0; k < 4; ++k) {
                const unsigned c = cc + (unsigned)k;
                v[k] = P[(c < 27u) ? (b0 + c) : (b1 + c - 27u)];
            }
            *(vfloat4*)(outc + t + 1024u * j) = v;
        }
    }
}

extern "C" void kernel_launch(void* const* d_in, const int* in_sizes, int n_in,
                              void* d_out, int out_size, void* d_ws, size_t ws_size,
                              hipStream_t stream) {
    const int*   idx = (const int*)d_in[0];   // bigram_idx [4194304] int32
    const float* W   = (const float*)d_in[1]; // W [601,27] float32
    float4*      out = (float4*)d_out;        // probs [4194304,27] float32

    // 512 blocks x 55296 float4 = 28311552 = out_size/16 exactly; no tail.
    trigram_probs_kernel<<<dim3(512), dim3(1024), 0, stream>>>(idx, W, out);
}